// Round 16
// baseline (4041.570 us; speedup 1.0000x reference)
//
#include <hip/hip_runtime.h>
#include <cstdint>
#include <cstddef>

#define NN 8192
#define D_IN 1024
#define DD 512
#define NE 131072
#define KK 8

#define STRIPW 2048
#define NSTRIP 4
#define CPS 24
#define NCAND 96

#define EPS_BASE 0.0035
#define EPS_MARK 0.10
#define DMAX_HEDGE 0.066f

typedef unsigned long long u64;
typedef unsigned int u32;
typedef unsigned short ushortx;
typedef __attribute__((ext_vector_type(8))) short short8v;
typedef __attribute__((ext_vector_type(16))) float f32x16;

__device__ __forceinline__ float lrelu32(float v) { return v >= 0.0f ? v : 0.2f * v; }

__device__ __forceinline__ u64 enc_dist(double dist) {
  u64 b = (u64)__double_as_longlong(dist);
  b = (b >> 63) ? ~b : (b | 0x8000000000000000ull);
  return b & 0xFFFFFFFFFFFFE000ull;
}
__device__ __forceinline__ double dec_key(u64 k) {
  u64 ub = k & 0xFFFFFFFFFFFFE000ull;
  u64 b = (ub >> 63) ? (ub & 0x7FFFFFFFFFFFFFFFull) : ~ub;
  return __longlong_as_double((long long)b);
}
__device__ __forceinline__ u32 enc_f32(float d) {
  u32 ub = __float_as_uint(d);
  return (ub & 0x80000000u) ? ~ub : (ub | 0x80000000u);
}
__device__ __forceinline__ ushortx f2bf(float f) {
  u32 u = __float_as_uint(f);
  return (ushortx)((u + 0x7FFFu + ((u >> 16) & 1u)) >> 16);
}
__device__ __forceinline__ float bf2f(ushortx s) { return __uint_as_float(((u32)s) << 16); }

// ---------------- tiled GEMM: fp32 in/out, fp64 accumulate -- double-buffered (bit-exact chain) ----------------
template<int ACT>
__global__ __launch_bounds__(256) void gemm_bias_act(
    const float* __restrict__ A, const float* __restrict__ W,
    const float* __restrict__ bias, float* __restrict__ C,
    int K, int Nc) {
  __shared__ float As[2][16][68];
  __shared__ float Bs[2][16][68];
  const int tid = threadIdx.x;
  const int tx = tid & 15, ty = tid >> 4;
  const int row0 = blockIdx.y * 64, col0 = blockIdx.x * 64;
  const int ar = tid >> 2, akq = (tid & 3) << 2;
  const int br = tid >> 4, bc = (tid & 15) << 2;
  double acc[4][4] = {};
  {
    const float4 av = *reinterpret_cast<const float4*>(&A[(size_t)(row0 + ar) * K + akq]);
    As[0][akq + 0][ar] = av.x; As[0][akq + 1][ar] = av.y; As[0][akq + 2][ar] = av.z; As[0][akq + 3][ar] = av.w;
    const float4 bv = *reinterpret_cast<const float4*>(&W[(size_t)br * Nc + (col0 + bc)]);
    Bs[0][br][bc + 0] = bv.x; Bs[0][br][bc + 1] = bv.y; Bs[0][br][bc + 2] = bv.z; Bs[0][br][bc + 3] = bv.w;
  }
  __syncthreads();
  int buf = 0;
  for (int k0 = 0; k0 < K; k0 += 16) {
    float4 av, bv;
    const bool more = (k0 + 16) < K;
    if (more) {
      av = *reinterpret_cast<const float4*>(&A[(size_t)(row0 + ar) * K + (k0 + 16 + akq)]);
      bv = *reinterpret_cast<const float4*>(&W[(size_t)(k0 + 16 + br) * Nc + (col0 + bc)]);
    }
#pragma unroll
    for (int kk = 0; kk < 16; ++kk) {
      const float4 a4 = *reinterpret_cast<const float4*>(&As[buf][kk][ty << 2]);
      const float4 b4 = *reinterpret_cast<const float4*>(&Bs[buf][kk][tx << 2]);
      double a[4], b[4];
      a[0] = (double)a4.x; a[1] = (double)a4.y; a[2] = (double)a4.z; a[3] = (double)a4.w;
      b[0] = (double)b4.x; b[1] = (double)b4.y; b[2] = (double)b4.z; b[3] = (double)b4.w;
#pragma unroll
      for (int i = 0; i < 4; ++i)
#pragma unroll
        for (int j = 0; j < 4; ++j) acc[i][j] = fma(a[i], b[j], acc[i][j]);
    }
    if (more) {
      const int nb = buf ^ 1;
      As[nb][akq + 0][ar] = av.x; As[nb][akq + 1][ar] = av.y; As[nb][akq + 2][ar] = av.z; As[nb][akq + 3][ar] = av.w;
      Bs[nb][br][bc + 0] = bv.x; Bs[nb][br][bc + 1] = bv.y; Bs[nb][br][bc + 2] = bv.z; Bs[nb][br][bc + 3] = bv.w;
      __syncthreads();
      buf = nb;
    }
  }
#pragma unroll
  for (int i = 0; i < 4; ++i) {
    const int r = row0 + (ty << 2) + i;
#pragma unroll
    for (int j = 0; j < 4; ++j) {
      const int c = col0 + (tx << 2) + j;
      double v = acc[i][j] + (double)bias[c];
      if (ACT) v = fmin(fmax(v, 0.0), 6.0);
      C[(size_t)r * Nc + c] = (float)v;
    }
  }
}

// ---------------- row squared norms ----------------
__global__ __launch_bounds__(256) void row_sqnorm_d(const float* __restrict__ H,
                                                    double* __restrict__ sqd,
                                                    float* __restrict__ sqf) {
  const int row = blockIdx.x * 4 + (threadIdx.x >> 6);
  const int lane = threadIdx.x & 63;
  const float* h = H + (size_t)row * DD;
  double s = 0.0;
#pragma unroll
  for (int b = 0; b < DD; b += 256) {
    const float4 v = *reinterpret_cast<const float4*>(&h[b + lane * 4]);
    s += (double)v.x * v.x + (double)v.y * v.y + (double)v.z * v.z + (double)v.w * v.w;
  }
#pragma unroll
  for (int o = 32; o > 0; o >>= 1) s += __shfl_down(s, o);
  if (lane == 0) { sqd[row] = s; sqf[row] = (float)s; }
}

// ---------------- split H into hi/lo bf16 ----------------
__global__ __launch_bounds__(256) void hsplit(const float* __restrict__ H,
                                              ushortx* __restrict__ Hhi, ushortx* __restrict__ Hlo) {
  const int base = (blockIdx.x * 256 + threadIdx.x) * 4;
  const float4 v = *reinterpret_cast<const float4*>(&H[base]);
  ushortx hi[4], lo[4];
  const float f[4] = {v.x, v.y, v.z, v.w};
#pragma unroll
  for (int q = 0; q < 4; ++q) {
    hi[q] = f2bf(f[q]);
    lo[q] = f2bf(f[q] - bf2f(hi[q]));
  }
  *reinterpret_cast<ushort4*>(&Hhi[base]) = make_ushort4(hi[0], hi[1], hi[2], hi[3]);
  *reinterpret_cast<ushort4*>(&Hlo[base]) = make_ushort4(lo[0], lo[1], lo[2], lo[3]);
}

// ---------------- MFMA split-bf16 Gram strip ----------------
__global__ __launch_bounds__(256) void gram_strip(
    const ushortx* __restrict__ Hhi, const ushortx* __restrict__ Hlo,
    const float* __restrict__ sqf, int jbase, float* __restrict__ Dst) {
  __shared__ uint4 Ah4[256], Al4[256], Bh4[256], Bl4[256];
  const int tid = threadIdx.x;
  const int w = tid >> 6, lane = tid & 63;
  const int wr = w >> 1, wc = w & 1;
  const int i0 = blockIdx.y * 64;
  const int j0 = jbase + blockIdx.x * 64;
  const int rh = tid >> 7, skk = (tid >> 6) & 1, sg = (tid >> 5) & 1, sr = tid & 31;
  const size_t arow = (size_t)(i0 + rh * 32 + sr) * DD;
  const size_t brow = (size_t)(j0 + rh * 32 + sr) * DD;
  const int koff = skk * 16 + sg * 8;
  f32x16 acc0, acc1;
#pragma unroll
  for (int e = 0; e < 16; ++e) { acc0[e] = 0.0f; acc1[e] = 0.0f; }

  for (int k0 = 0; k0 < DD; k0 += 32) {
    __syncthreads();
    Ah4[tid] = *reinterpret_cast<const uint4*>(&Hhi[arow + k0 + koff]);
    Al4[tid] = *reinterpret_cast<const uint4*>(&Hlo[arow + k0 + koff]);
    Bh4[tid] = *reinterpret_cast<const uint4*>(&Hhi[brow + k0 + koff]);
    Bl4[tid] = *reinterpret_cast<const uint4*>(&Hlo[brow + k0 + koff]);
    __syncthreads();
    const short8v* Ah = reinterpret_cast<const short8v*>(Ah4);
    const short8v* Al = reinterpret_cast<const short8v*>(Al4);
    const short8v* Bh = reinterpret_cast<const short8v*>(Bh4);
    const short8v* Bl = reinterpret_cast<const short8v*>(Bl4);
    const short8v ah0 = Ah[(wr * 2 + 0) * 64 + lane];
    const short8v ah1 = Ah[(wr * 2 + 1) * 64 + lane];
    const short8v al0 = Al[(wr * 2 + 0) * 64 + lane];
    const short8v al1 = Al[(wr * 2 + 1) * 64 + lane];
    const short8v bh0 = Bh[(wc * 2 + 0) * 64 + lane];
    const short8v bh1 = Bh[(wc * 2 + 1) * 64 + lane];
    const short8v bl0 = Bl[(wc * 2 + 0) * 64 + lane];
    const short8v bl1 = Bl[(wc * 2 + 1) * 64 + lane];
    acc0 = __builtin_amdgcn_mfma_f32_32x32x16_bf16(ah0, bh0, acc0, 0, 0, 0);
    acc0 = __builtin_amdgcn_mfma_f32_32x32x16_bf16(ah1, bh1, acc0, 0, 0, 0);
    acc0 = __builtin_amdgcn_mfma_f32_32x32x16_bf16(al0, bh0, acc0, 0, 0, 0);
    acc1 = __builtin_amdgcn_mfma_f32_32x32x16_bf16(al1, bh1, acc1, 0, 0, 0);
    acc1 = __builtin_amdgcn_mfma_f32_32x32x16_bf16(ah0, bl0, acc1, 0, 0, 0);
    acc1 = __builtin_amdgcn_mfma_f32_32x32x16_bf16(ah1, bl1, acc1, 0, 0, 0);
  }
  const int ccol = j0 + wc * 32 + (lane & 31);
  const float sqc = sqf[ccol];
#pragma unroll
  for (int reg = 0; reg < 16; ++reg) {
    const int row = i0 + wr * 32 + (reg & 3) + 8 * (reg >> 2) + 4 * (lane >> 5);
    const float G = acc0[reg] + acc1[reg];
    float d = (sqf[row] - 2.0f * G) + sqc;
    if (row == ccol) d = INFINITY;
    Dst[(size_t)row * STRIPW + (ccol - jbase)] = d;
  }
}

// ---------------- per-row strip scan ----------------
__global__ __launch_bounds__(256) void knn_scan(
    const float* __restrict__ Dst, int jbase, int* __restrict__ cand, int soff) {
  const int w = threadIdx.x >> 6, lane = threadIdx.x & 63;
  const int row = blockIdx.x * 4 + w;
  const float* dr = Dst + (size_t)row * STRIPW;
  u64 best[8];
#pragma unroll
  for (int s = 0; s < 8; ++s) best[s] = ~0ull;
#pragma unroll
  for (int it = 0; it < STRIPW / 256; ++it) {
    const int cbase = it * 256 + lane * 4;
    const float4 v = *reinterpret_cast<const float4*>(&dr[cbase]);
    const float f[4] = {v.x, v.y, v.z, v.w};
#pragma unroll
    for (int q = 0; q < 4; ++q) {
      const u64 key = ((u64)enc_f32(f[q]) << 32) | (u32)(jbase + cbase + q);
      if (key < best[7]) {
        best[7] = key;
#pragma unroll
        for (int s = 7; s >= 1; --s) {
          if (best[s] < best[s - 1]) { const u64 t = best[s]; best[s] = best[s - 1]; best[s - 1] = t; }
        }
      }
    }
  }
  for (int t = 0; t < CPS; ++t) {
    u64 m = best[0];
#pragma unroll
    for (int o = 32; o > 0; o >>= 1) {
      const u64 x = __shfl_xor(m, o);
      m = (x < m) ? x : m;
    }
    const unsigned long long mask = __ballot(best[0] == m);
    const int owner = __ffsll(mask) - 1;
    if (lane == owner) {
#pragma unroll
      for (int s = 0; s < 7; ++s) best[s] = best[s + 1];
      best[7] = ~0ull;
    }
    if (lane == 0) cand[(size_t)row * NCAND + soff + t] = (int)(m & 0x1FFFull);
  }
}

// ---------------- EXACT refinement: fp64 sequential dot, TWO rows per block (2x chain ILP) ----------------
// Per-candidate chain order (scalar loads, k ascending) identical to r14's 294us version.
__global__ __launch_bounds__(128) void knn_refine10(
    const float* __restrict__ H, const double* __restrict__ sqd,
    const int* __restrict__ cand, u64* __restrict__ keys10) {
  const int iA = blockIdx.x;
  const int iB = blockIdx.x + NN / 2;
  const int lane = threadIdx.x;
  __shared__ float hia[DD], hib[DD];
  __shared__ u64 ksA[128], ksB[128];
  for (int d = lane; d < DD; d += 128) {
    hia[d] = H[(size_t)iA * DD + d];
    hib[d] = H[(size_t)iB * DD + d];
  }
  __syncthreads();
  u64 keyA = ~0ull, keyB = ~0ull;
  if (lane < NCAND) {
    const int jA = cand[(size_t)iA * NCAND + lane];
    const int jB = cand[(size_t)iB * NCAND + lane];
    const float* hjA = H + (size_t)jA * DD;
    const float* hjB = H + (size_t)jB * DD;
    double accA = 0.0, accB = 0.0;
#pragma unroll 16
    for (int k = 0; k < DD; ++k) {
      accA = fma((double)hia[k], (double)hjA[k], accA);
      accB = fma((double)hib[k], (double)hjB[k], accB);
    }
    if (jA != iA) keyA = enc_dist((sqd[iA] - 2.0 * accA) + sqd[jA]) | (u64)(u32)jA;
    if (jB != iB) keyB = enc_dist((sqd[iB] - 2.0 * accB) + sqd[jB]) | (u64)(u32)jB;
  }
  ksA[lane] = keyA;
  ksB[lane] = keyB;
  __syncthreads();
  if (lane == 0 || lane == 64) {
    const u64* ks = (lane == 0) ? ksA : ksB;
    const int i = (lane == 0) ? iA : iB;
    u64 out[10];
#pragma unroll
    for (int s = 0; s < 10; ++s) out[s] = ~0ull;
    for (int m = 0; m < 128; ++m) {
      const u64 k = ks[m];
      if (k < out[9]) {
        int pos = 9;
        while (pos > 0 && out[pos - 1] > k) { out[pos] = out[pos - 1]; --pos; }
        out[pos] = k;
      }
    }
#pragma unroll
    for (int s = 0; s < 10; ++s) keys10[(size_t)i * 10 + s] = out[s];
  }
}

// ---------------- CSR build ----------------
__global__ void zero_ints(int* __restrict__ p, int n) {
  const int i = blockIdx.x * 256 + threadIdx.x;
  if (i < n) p[i] = 0;
}
__global__ void hist_tgt(const int* __restrict__ tgt, int* __restrict__ deg) {
  const int e = blockIdx.x * 256 + threadIdx.x;
  if (e < NE) atomicAdd(&deg[tgt[e]], 1);
}
__global__ __launch_bounds__(1024) void scan_deg(const int* __restrict__ deg, int* __restrict__ off) {
  __shared__ int ps[1024];
  const int tid = threadIdx.x;
  const int base = tid * 8;
  int v[8];
  int s = 0;
#pragma unroll
  for (int q = 0; q < 8; ++q) { v[q] = deg[base + q]; s += v[q]; }
  ps[tid] = s;
  __syncthreads();
  for (int d = 1; d < 1024; d <<= 1) {
    const int add = (tid >= d) ? ps[tid - d] : 0;
    __syncthreads();
    ps[tid] += add;
    __syncthreads();
  }
  int run = (tid == 0) ? 0 : ps[tid - 1];
#pragma unroll
  for (int q = 0; q < 8; ++q) { off[base + q] = run; run += v[q]; }
  if (tid == 1023) off[NN] = run;
}
__global__ void scatter_edges(const int* __restrict__ tgt, const int* __restrict__ off,
                              int* __restrict__ cur, int* __restrict__ perm) {
  const int e = blockIdx.x * 256 + threadIdx.x;
  if (e < NE) {
    const int t = tgt[e];
    const int p = atomicAdd(&cur[t], 1);
    perm[off[t] + p] = e;
  }
}

// ---------------- spatial edge logits ----------------
__global__ __launch_bounds__(256) void edge_logits_sp(
    const float* __restrict__ xl, const float* __restrict__ xr,
    const float* __restrict__ att, const float* __restrict__ we,
    const float* __restrict__ ea, const int* __restrict__ srcv, const int* __restrict__ tgtv,
    float* __restrict__ logits) {
  const int e = blockIdx.x * 4 + (threadIdx.x >> 6);
  const int lane = threadIdx.x & 63;
  const int s = srcv[e], t = tgtv[e];
  const float w = ea[e];
  const float* pl = xl + (size_t)s * DD;
  const float* pr = xr + (size_t)t * DD;
  double acc = 0.0;
#pragma unroll
  for (int b = 0; b < DD; b += 256) {
    const int d = b + lane * 4;
    const float4 a4 = *reinterpret_cast<const float4*>(&pl[d]);
    const float4 r4 = *reinterpret_cast<const float4*>(&pr[d]);
    const float4 w4 = *reinterpret_cast<const float4*>(&we[d]);
    const float4 t4 = *reinterpret_cast<const float4*>(&att[d]);
    acc += (double)t4.x * (double)lrelu32(a4.x + r4.x + w * w4.x);
    acc += (double)t4.y * (double)lrelu32(a4.y + r4.y + w * w4.y);
    acc += (double)t4.z * (double)lrelu32(a4.z + r4.z + w * w4.z);
    acc += (double)t4.w * (double)lrelu32(a4.w + r4.w + w * w4.w);
  }
#pragma unroll
  for (int o = 32; o > 0; o >>= 1) acc += __shfl_down(acc, o);
  if (lane == 0) logits[e] = (float)acc;
}

// ---------------- fused per-target: spatial softmax-agg + hedged latent GAT + relu6 ----------------
__global__ __launch_bounds__(256) void gat_aggregate_fused(
    const float* __restrict__ xls, const float* __restrict__ lgsp,
    const int* __restrict__ off, const int* __restrict__ perm, const int* __restrict__ srcv,
    const float* __restrict__ bias_sp,
    const float* __restrict__ xll, const float* __restrict__ xrl,
    const float* __restrict__ att,
    const u64* __restrict__ keys10, const int* __restrict__ flg_in, int* __restrict__ flg_out,
    const float* __restrict__ bias_lat, float* __restrict__ hout) {
  const int t = blockIdx.x;
  const int tid = threadIdx.x;
  const int lane = tid & 63, wid = tid >> 6;
  __shared__ double lg[9];
  __shared__ double sm[2];
  __shared__ int nidx[10];
  __shared__ int marked;
  __shared__ double gap;
  __shared__ float red[256];
  if (tid < 10) nidx[tid] = (int)(keys10[(size_t)t * 10 + tid] & 0x1FFFull);
  if (tid == 0) gap = dec_key(keys10[(size_t)t * 10 + 8]) - dec_key(keys10[(size_t)t * 10 + 7]);
  __syncthreads();
  if (tid == 0) {
    int m = flg_in[t];
#pragma unroll
    for (int q = 0; q < 10; ++q) m |= flg_in[nidx[q]];
    marked = m;
  }
  const float* pr = xrl + (size_t)t * DD;
  for (int q = wid; q < 9; q += 4) {
    const float* pl = xll + (size_t)nidx[q] * DD;
    double acc = 0.0;
#pragma unroll
    for (int b = 0; b < DD; b += 256) {
      const int d = b + lane * 4;
      const float4 a4 = *reinterpret_cast<const float4*>(&pl[d]);
      const float4 r4 = *reinterpret_cast<const float4*>(&pr[d]);
      const float4 t4 = *reinterpret_cast<const float4*>(&att[d]);
      acc += (double)t4.x * (double)lrelu32(a4.x + r4.x);
      acc += (double)t4.y * (double)lrelu32(a4.y + r4.y);
      acc += (double)t4.z * (double)lrelu32(a4.z + r4.z);
      acc += (double)t4.w * (double)lrelu32(a4.w + r4.w);
    }
#pragma unroll
    for (int o = 32; o > 0; o >>= 1) acc += __shfl_down(acc, o);
    if (lane == 0) lg[q] = acc;
  }
  const int o0 = off[t];
  const int deg = off[t + 1] - o0;
  if (tid < 64 && deg > 0) {
    double mx = -INFINITY;
    for (int m = lane; m < deg; m += 64) mx = fmax(mx, (double)lgsp[perm[o0 + m]]);
#pragma unroll
    for (int o = 32; o > 0; o >>= 1) mx = fmax(mx, __shfl_down(mx, o));
    mx = __shfl(mx, 0);
    double ss = 0.0;
    for (int m = lane; m < deg; m += 64) ss += exp((double)lgsp[perm[o0 + m]] - mx);
#pragma unroll
    for (int o = 32; o > 0; o >>= 1) ss += __shfl_down(ss, o);
    if (lane == 0) { sm[0] = mx; sm[1] = ss; }
  }
  __syncthreads();
  double a0 = 0.0, a1 = 0.0;
  if (deg > 0) {
    const double mx = sm[0], stot = sm[1];
    for (int m = 0; m < deg; ++m) {
      const int e = perm[o0 + m];
      const int s = srcv[e];
      const double a = exp((double)lgsp[e] - mx) / stot;
      a0 = fma(a, (double)xls[(size_t)s * DD + tid], a0);
      a1 = fma(a, (double)xls[(size_t)s * DD + 256 + tid], a1);
    }
  }
  double mA = lg[0], mB = lg[8];
#pragma unroll
  for (int q = 1; q < 8; ++q) mA = fmax(mA, lg[q]);
#pragma unroll
  for (int q = 0; q < 7; ++q) mB = fmax(mB, lg[q]);
  double eA[8], eB[8];
  double sA = 0.0, sB = 0.0;
#pragma unroll
  for (int q = 0; q < 8; ++q) { eA[q] = exp(lg[q] - mA); sA += eA[q]; }
#pragma unroll
  for (int q = 0; q < 7; ++q) { eB[q] = exp(lg[q] - mB); sB += eB[q]; }
  eB[7] = exp(lg[8] - mB); sB += eB[7];
  double A0 = 0.0, A1 = 0.0, B0 = 0.0, B1 = 0.0;
#pragma unroll
  for (int q = 0; q < 8; ++q) {
    const double x0 = (double)xll[(size_t)nidx[q] * DD + tid];
    const double x1 = (double)xll[(size_t)nidx[q] * DD + 256 + tid];
    A0 = fma(eA[q], x0, A0);
    A1 = fma(eA[q], x1, A1);
    if (q < 7) { B0 = fma(eB[q], x0, B0); B1 = fma(eB[q], x1, B1); }
  }
  {
    const double x0 = (double)xll[(size_t)nidx[8] * DD + tid];
    const double x1 = (double)xll[(size_t)nidx[8] * DD + 256 + tid];
    B0 = fma(eB[7], x0, B0);
    B1 = fma(eB[7], x1, B1);
  }
  const double sp0 = a0 + (double)bias_sp[tid];
  const double sp1 = a1 + (double)bias_sp[tid + 256];
  const double bl0 = (double)bias_lat[tid];
  const double bl1 = (double)bias_lat[tid + 256];
  const double vA0 = fmin(fmax(sp0 + (A0 / sA + bl0), 0.0), 6.0);
  const double vA1 = fmin(fmax(sp1 + (A1 / sA + bl1), 0.0), 6.0);
  const double vB0 = fmin(fmax(sp0 + (B0 / sB + bl0), 0.0), 6.0);
  const double vB1 = fmin(fmax(sp1 + (B1 / sB + bl1), 0.0), 6.0);
  red[tid] = fmaxf((float)fabs(vA0 - vB0), (float)fabs(vA1 - vB1));
  __syncthreads();
  for (int s = 128; s > 0; s >>= 1) {
    if (tid < s) red[tid] = fmaxf(red[tid], red[tid + s]);
    __syncthreads();
  }
  const double eps = marked ? EPS_MARK : EPS_BASE;
  const double w = (gap < eps && red[0] <= DMAX_HEDGE) ? 0.5 : 0.0;
  if (tid == 0) flg_out[t] = (w > 0.0) ? 1 : 0;
  hout[(size_t)t * DD + tid]       = (float)((1.0 - w) * vA0 + w * vB0);
  hout[(size_t)t * DD + 256 + tid] = (float)((1.0 - w) * vA1 + w * vB1);
}

extern "C" void kernel_launch(void* const* d_in, const int* in_sizes, int n_in,
                              void* d_out, int out_size, void* d_ws, size_t ws_size,
                              hipStream_t stream) {
  const float* x       = (const float*)d_in[0];
  const float* ea      = (const float*)d_in[1];
  const float* W0      = (const float*)d_in[2];
  const float* b0      = (const float*)d_in[3];
  const float* W1      = (const float*)d_in[4];
  const float* b1      = (const float*)d_in[5];
  const float* W2      = (const float*)d_in[6];
  const float* b2      = (const float*)d_in[7];
  const float* Wl_sp   = (const float*)d_in[8];
  const float* bl_sp   = (const float*)d_in[9];
  const float* Wr_sp   = (const float*)d_in[10];
  const float* br_sp   = (const float*)d_in[11];
  const float* att_sp  = (const float*)d_in[12];
  const float* bias_sp = (const float*)d_in[13];
  const float* We_sp   = (const float*)d_in[14];
  const float* Wl_lat  = (const float*)d_in[15];
  const float* bl_lat  = (const float*)d_in[16];
  const float* Wr_lat  = (const float*)d_in[17];
  const float* br_lat  = (const float*)d_in[18];
  const float* att_lat = (const float*)d_in[19];
  const float* bias_lat= (const float*)d_in[20];
  const int*   eidx    = (const int*)d_in[21];
  const int* srcv = eidx;
  const int* tgtv = eidx + NE;

  char* ws = (char*)d_ws;
  size_t off = 0;
  auto alloc = [&](size_t bytes) -> void* {
    void* p = ws + off;
    off = (off + bytes + 255) & ~(size_t)255;
    return p;
  };
  float* h0     = (float*)alloc((size_t)NN * DD * 4);
  float* h1     = (float*)alloc((size_t)NN * DD * 4);
  float* xls    = (float*)alloc((size_t)NN * DD * 4);
  float* xrs    = (float*)alloc((size_t)NN * DD * 4);
  float* xll    = (float*)alloc((size_t)NN * DD * 4);
  float* xrl    = (float*)alloc((size_t)NN * DD * 4);
  float* logits = (float*)alloc((size_t)NE * 4);
  double* sqd   = (double*)alloc((size_t)NN * 8);
  float* sqf    = (float*)alloc((size_t)NN * 4);
  ushortx* Hhi  = (ushortx*)alloc((size_t)NN * DD * 2);
  ushortx* Hlo  = (ushortx*)alloc((size_t)NN * DD * 2);
  float* Dst    = (float*)alloc((size_t)NN * STRIPW * 4);
  int* cand     = (int*)alloc((size_t)NN * NCAND * 4);
  u64* keys10   = (u64*)alloc((size_t)NN * 10 * 8);
  int* flags0   = (int*)alloc((size_t)NN * 4);
  int* flags1   = (int*)alloc((size_t)NN * 4);
  int* flags2   = (int*)alloc((size_t)NN * 4);
  int* deg      = (int*)alloc((size_t)NN * 4);
  int* offs     = (int*)alloc((size_t)(NN + 1) * 4);
  int* cur      = (int*)alloc((size_t)NN * 4);
  int* perm     = (int*)alloc((size_t)NE * 4);
  float* t1 = xls;
  float* t2 = xrs;

  // MLP encoder
  gemm_bias_act<1><<<dim3(512 / 64, NN / 64), 256, 0, stream>>>(x, W0, b0, t1, D_IN, 512);
  gemm_bias_act<1><<<dim3(256 / 64, NN / 64), 256, 0, stream>>>(t1, W1, b1, t2, 512, 256);
  gemm_bias_act<0><<<dim3(512 / 64, NN / 64), 256, 0, stream>>>(t2, W2, b2, h0, 256, 512);

  // CSR of spatial edges by target
  zero_ints<<<NN / 256, 256, 0, stream>>>(deg, NN);
  zero_ints<<<NN / 256, 256, 0, stream>>>(cur, NN);
  zero_ints<<<NN / 256, 256, 0, stream>>>(flags0, NN);
  hist_tgt<<<NE / 256, 256, 0, stream>>>(tgtv, deg);
  scan_deg<<<1, 1024, 0, stream>>>(deg, offs);
  scatter_edges<<<NE / 256, 256, 0, stream>>>(tgtv, offs, cur, perm);

  for (int l = 0; l < 2; ++l) {
    const float* hin = l ? h1 : h0;
    float* hout = l ? (float*)d_out : h1;
    const int* fin  = l ? flags1 : flags0;
    int* fout       = l ? flags2 : flags1;
    const size_t wofs = (size_t)l * DD * DD;
    const size_t vofs = (size_t)l * DD;
    gemm_bias_act<0><<<dim3(8, 128), 256, 0, stream>>>(hin, Wl_sp + wofs, bl_sp + vofs, xls, DD, DD);
    gemm_bias_act<0><<<dim3(8, 128), 256, 0, stream>>>(hin, Wr_sp + wofs, br_sp + vofs, xrs, DD, DD);
    gemm_bias_act<0><<<dim3(8, 128), 256, 0, stream>>>(hin, Wl_lat + wofs, bl_lat + vofs, xll, DD, DD);
    gemm_bias_act<0><<<dim3(8, 128), 256, 0, stream>>>(hin, Wr_lat + wofs, br_lat + vofs, xrl, DD, DD);
    row_sqnorm_d<<<NN / 4, 256, 0, stream>>>(hin, sqd, sqf);
    hsplit<<<(NN * DD / 4) / 256, 256, 0, stream>>>(hin, Hhi, Hlo);
    for (int s = 0; s < NSTRIP; ++s) {
      gram_strip<<<dim3(STRIPW / 64, NN / 64), 256, 0, stream>>>(Hhi, Hlo, sqf, s * STRIPW, Dst);
      knn_scan<<<NN / 4, 256, 0, stream>>>(Dst, s * STRIPW, cand, s * CPS);
    }
    knn_refine10<<<NN / 2, 128, 0, stream>>>(hin, sqd, cand, keys10);
    edge_logits_sp<<<NE / 4, 256, 0, stream>>>(xls, xrs, att_sp + vofs, We_sp + vofs, ea, srcv, tgtv, logits);
    gat_aggregate_fused<<<NN, 256, 0, stream>>>(
        xls, logits, offs, perm, srcv, bias_sp + vofs,
        xll, xrl, att_lat + vofs, keys10, fin, fout, bias_lat + vofs, hout);
  }
}

// Round 17
// 3752.943 us; speedup vs baseline: 1.0769x; 1.0769x over previous
//
#include <hip/hip_runtime.h>
#include <cstdint>
#include <cstddef>

#define NN 8192
#define D_IN 1024
#define DD 512
#define NE 131072
#define KK 8

#define STRIPW 2048
#define NSTRIP 4
#define CPS 24
#define NCAND 96

#define EPS_BASE 0.0035
#define EPS_MARK 0.10
#define DMAX_HEDGE 0.066f

typedef unsigned long long u64;
typedef unsigned int u32;
typedef unsigned short ushortx;
typedef __attribute__((ext_vector_type(8))) short short8v;
typedef __attribute__((ext_vector_type(16))) float f32x16;

__device__ __forceinline__ float lrelu32(float v) { return v >= 0.0f ? v : 0.2f * v; }

__device__ __forceinline__ u64 enc_dist(double dist) {
  u64 b = (u64)__double_as_longlong(dist);
  b = (b >> 63) ? ~b : (b | 0x8000000000000000ull);
  return b & 0xFFFFFFFFFFFFE000ull;
}
__device__ __forceinline__ double dec_key(u64 k) {
  u64 ub = k & 0xFFFFFFFFFFFFE000ull;
  u64 b = (ub >> 63) ? (ub & 0x7FFFFFFFFFFFFFFFull) : ~ub;
  return __longlong_as_double((long long)b);
}
__device__ __forceinline__ u32 enc_f32(float d) {
  u32 ub = __float_as_uint(d);
  return (ub & 0x80000000u) ? ~ub : (ub | 0x80000000u);
}
__device__ __forceinline__ ushortx f2bf(float f) {
  u32 u = __float_as_uint(f);
  return (ushortx)((u + 0x7FFFu + ((u >> 16) & 1u)) >> 16);
}
__device__ __forceinline__ float bf2f(ushortx s) { return __uint_as_float(((u32)s) << 16); }

// ---------------- tiled GEMM: fp32 in/out, fp64 accumulate -- double-buffered (bit-exact chain) ----------------
template<int ACT>
__global__ __launch_bounds__(256) void gemm_bias_act(
    const float* __restrict__ A, const float* __restrict__ W,
    const float* __restrict__ bias, float* __restrict__ C,
    int K, int Nc) {
  __shared__ float As[2][16][68];
  __shared__ float Bs[2][16][68];
  const int tid = threadIdx.x;
  const int tx = tid & 15, ty = tid >> 4;
  const int row0 = blockIdx.y * 64, col0 = blockIdx.x * 64;
  const int ar = tid >> 2, akq = (tid & 3) << 2;
  const int br = tid >> 4, bc = (tid & 15) << 2;
  double acc[4][4] = {};
  {
    const float4 av = *reinterpret_cast<const float4*>(&A[(size_t)(row0 + ar) * K + akq]);
    As[0][akq + 0][ar] = av.x; As[0][akq + 1][ar] = av.y; As[0][akq + 2][ar] = av.z; As[0][akq + 3][ar] = av.w;
    const float4 bv = *reinterpret_cast<const float4*>(&W[(size_t)br * Nc + (col0 + bc)]);
    Bs[0][br][bc + 0] = bv.x; Bs[0][br][bc + 1] = bv.y; Bs[0][br][bc + 2] = bv.z; Bs[0][br][bc + 3] = bv.w;
  }
  __syncthreads();
  int buf = 0;
  for (int k0 = 0; k0 < K; k0 += 16) {
    float4 av, bv;
    const bool more = (k0 + 16) < K;
    if (more) {
      av = *reinterpret_cast<const float4*>(&A[(size_t)(row0 + ar) * K + (k0 + 16 + akq)]);
      bv = *reinterpret_cast<const float4*>(&W[(size_t)(k0 + 16 + br) * Nc + (col0 + bc)]);
    }
#pragma unroll
    for (int kk = 0; kk < 16; ++kk) {
      const float4 a4 = *reinterpret_cast<const float4*>(&As[buf][kk][ty << 2]);
      const float4 b4 = *reinterpret_cast<const float4*>(&Bs[buf][kk][tx << 2]);
      double a[4], b[4];
      a[0] = (double)a4.x; a[1] = (double)a4.y; a[2] = (double)a4.z; a[3] = (double)a4.w;
      b[0] = (double)b4.x; b[1] = (double)b4.y; b[2] = (double)b4.z; b[3] = (double)b4.w;
#pragma unroll
      for (int i = 0; i < 4; ++i)
#pragma unroll
        for (int j = 0; j < 4; ++j) acc[i][j] = fma(a[i], b[j], acc[i][j]);
    }
    if (more) {
      const int nb = buf ^ 1;
      As[nb][akq + 0][ar] = av.x; As[nb][akq + 1][ar] = av.y; As[nb][akq + 2][ar] = av.z; As[nb][akq + 3][ar] = av.w;
      Bs[nb][br][bc + 0] = bv.x; Bs[nb][br][bc + 1] = bv.y; Bs[nb][br][bc + 2] = bv.z; Bs[nb][br][bc + 3] = bv.w;
      __syncthreads();
      buf = nb;
    }
  }
#pragma unroll
  for (int i = 0; i < 4; ++i) {
    const int r = row0 + (ty << 2) + i;
#pragma unroll
    for (int j = 0; j < 4; ++j) {
      const int c = col0 + (tx << 2) + j;
      double v = acc[i][j] + (double)bias[c];
      if (ACT) v = fmin(fmax(v, 0.0), 6.0);
      C[(size_t)r * Nc + c] = (float)v;
    }
  }
}

// ---------------- row squared norms ----------------
__global__ __launch_bounds__(256) void row_sqnorm_d(const float* __restrict__ H,
                                                    double* __restrict__ sqd,
                                                    float* __restrict__ sqf) {
  const int row = blockIdx.x * 4 + (threadIdx.x >> 6);
  const int lane = threadIdx.x & 63;
  const float* h = H + (size_t)row * DD;
  double s = 0.0;
#pragma unroll
  for (int b = 0; b < DD; b += 256) {
    const float4 v = *reinterpret_cast<const float4*>(&h[b + lane * 4]);
    s += (double)v.x * v.x + (double)v.y * v.y + (double)v.z * v.z + (double)v.w * v.w;
  }
#pragma unroll
  for (int o = 32; o > 0; o >>= 1) s += __shfl_down(s, o);
  if (lane == 0) { sqd[row] = s; sqf[row] = (float)s; }
}

// ---------------- split H into hi/lo bf16 ----------------
__global__ __launch_bounds__(256) void hsplit(const float* __restrict__ H,
                                              ushortx* __restrict__ Hhi, ushortx* __restrict__ Hlo) {
  const int base = (blockIdx.x * 256 + threadIdx.x) * 4;
  const float4 v = *reinterpret_cast<const float4*>(&H[base]);
  ushortx hi[4], lo[4];
  const float f[4] = {v.x, v.y, v.z, v.w};
#pragma unroll
  for (int q = 0; q < 4; ++q) {
    hi[q] = f2bf(f[q]);
    lo[q] = f2bf(f[q] - bf2f(hi[q]));
  }
  *reinterpret_cast<ushort4*>(&Hhi[base]) = make_ushort4(hi[0], hi[1], hi[2], hi[3]);
  *reinterpret_cast<ushort4*>(&Hlo[base]) = make_ushort4(lo[0], lo[1], lo[2], lo[3]);
}

// ---------------- MFMA split-bf16 Gram strip ----------------
__global__ __launch_bounds__(256) void gram_strip(
    const ushortx* __restrict__ Hhi, const ushortx* __restrict__ Hlo,
    const float* __restrict__ sqf, int jbase, float* __restrict__ Dst) {
  __shared__ uint4 Ah4[256], Al4[256], Bh4[256], Bl4[256];
  const int tid = threadIdx.x;
  const int w = tid >> 6, lane = tid & 63;
  const int wr = w >> 1, wc = w & 1;
  const int i0 = blockIdx.y * 64;
  const int j0 = jbase + blockIdx.x * 64;
  const int rh = tid >> 7, skk = (tid >> 6) & 1, sg = (tid >> 5) & 1, sr = tid & 31;
  const size_t arow = (size_t)(i0 + rh * 32 + sr) * DD;
  const size_t brow = (size_t)(j0 + rh * 32 + sr) * DD;
  const int koff = skk * 16 + sg * 8;
  f32x16 acc0, acc1;
#pragma unroll
  for (int e = 0; e < 16; ++e) { acc0[e] = 0.0f; acc1[e] = 0.0f; }

  for (int k0 = 0; k0 < DD; k0 += 32) {
    __syncthreads();
    Ah4[tid] = *reinterpret_cast<const uint4*>(&Hhi[arow + k0 + koff]);
    Al4[tid] = *reinterpret_cast<const uint4*>(&Hlo[arow + k0 + koff]);
    Bh4[tid] = *reinterpret_cast<const uint4*>(&Hhi[brow + k0 + koff]);
    Bl4[tid] = *reinterpret_cast<const uint4*>(&Hlo[brow + k0 + koff]);
    __syncthreads();
    const short8v* Ah = reinterpret_cast<const short8v*>(Ah4);
    const short8v* Al = reinterpret_cast<const short8v*>(Al4);
    const short8v* Bh = reinterpret_cast<const short8v*>(Bh4);
    const short8v* Bl = reinterpret_cast<const short8v*>(Bl4);
    const short8v ah0 = Ah[(wr * 2 + 0) * 64 + lane];
    const short8v ah1 = Ah[(wr * 2 + 1) * 64 + lane];
    const short8v al0 = Al[(wr * 2 + 0) * 64 + lane];
    const short8v al1 = Al[(wr * 2 + 1) * 64 + lane];
    const short8v bh0 = Bh[(wc * 2 + 0) * 64 + lane];
    const short8v bh1 = Bh[(wc * 2 + 1) * 64 + lane];
    const short8v bl0 = Bl[(wc * 2 + 0) * 64 + lane];
    const short8v bl1 = Bl[(wc * 2 + 1) * 64 + lane];
    acc0 = __builtin_amdgcn_mfma_f32_32x32x16_bf16(ah0, bh0, acc0, 0, 0, 0);
    acc0 = __builtin_amdgcn_mfma_f32_32x32x16_bf16(ah1, bh1, acc0, 0, 0, 0);
    acc0 = __builtin_amdgcn_mfma_f32_32x32x16_bf16(al0, bh0, acc0, 0, 0, 0);
    acc1 = __builtin_amdgcn_mfma_f32_32x32x16_bf16(al1, bh1, acc1, 0, 0, 0);
    acc1 = __builtin_amdgcn_mfma_f32_32x32x16_bf16(ah0, bl0, acc1, 0, 0, 0);
    acc1 = __builtin_amdgcn_mfma_f32_32x32x16_bf16(ah1, bl1, acc1, 0, 0, 0);
  }
  const int ccol = j0 + wc * 32 + (lane & 31);
  const float sqc = sqf[ccol];
#pragma unroll
  for (int reg = 0; reg < 16; ++reg) {
    const int row = i0 + wr * 32 + (reg & 3) + 8 * (reg >> 2) + 4 * (lane >> 5);
    const float G = acc0[reg] + acc1[reg];
    float d = (sqf[row] - 2.0f * G) + sqc;
    if (row == ccol) d = INFINITY;
    Dst[(size_t)row * STRIPW + (ccol - jbase)] = d;
  }
}

// ---------------- per-row strip scan ----------------
__global__ __launch_bounds__(256) void knn_scan(
    const float* __restrict__ Dst, int jbase, int* __restrict__ cand, int soff) {
  const int w = threadIdx.x >> 6, lane = threadIdx.x & 63;
  const int row = blockIdx.x * 4 + w;
  const float* dr = Dst + (size_t)row * STRIPW;
  u64 best[8];
#pragma unroll
  for (int s = 0; s < 8; ++s) best[s] = ~0ull;
#pragma unroll
  for (int it = 0; it < STRIPW / 256; ++it) {
    const int cbase = it * 256 + lane * 4;
    const float4 v = *reinterpret_cast<const float4*>(&dr[cbase]);
    const float f[4] = {v.x, v.y, v.z, v.w};
#pragma unroll
    for (int q = 0; q < 4; ++q) {
      const u64 key = ((u64)enc_f32(f[q]) << 32) | (u32)(jbase + cbase + q);
      if (key < best[7]) {
        best[7] = key;
#pragma unroll
        for (int s = 7; s >= 1; --s) {
          if (best[s] < best[s - 1]) { const u64 t = best[s]; best[s] = best[s - 1]; best[s - 1] = t; }
        }
      }
    }
  }
  for (int t = 0; t < CPS; ++t) {
    u64 m = best[0];
#pragma unroll
    for (int o = 32; o > 0; o >>= 1) {
      const u64 x = __shfl_xor(m, o);
      m = (x < m) ? x : m;
    }
    const unsigned long long mask = __ballot(best[0] == m);
    const int owner = __ffsll(mask) - 1;
    if (lane == owner) {
#pragma unroll
      for (int s = 0; s < 7; ++s) best[s] = best[s + 1];
      best[7] = ~0ull;
    }
    if (lane == 0) cand[(size_t)row * NCAND + soff + t] = (int)(m & 0x1FFFull);
  }
}

// ---------------- EXACT refinement: fp64 sequential dot (r14-proven form, 294us) ----------------
__global__ __launch_bounds__(128) void knn_refine10(
    const float* __restrict__ H, const double* __restrict__ sqd,
    const int* __restrict__ cand, u64* __restrict__ keys10) {
  const int i = blockIdx.x;
  const int lane = threadIdx.x;
  __shared__ float hi[DD];
  __shared__ u64 ks[128];
  for (int d = lane; d < DD; d += 128) hi[d] = H[(size_t)i * DD + d];
  __syncthreads();
  u64 key = ~0ull;
  if (lane < NCAND) {
    const int j = cand[(size_t)i * NCAND + lane];
    if (j != i) {
      const float* hj = H + (size_t)j * DD;
      double acc = 0.0;
#pragma unroll 16
      for (int k = 0; k < DD; ++k) acc = fma((double)hi[k], (double)hj[k], acc);
      const double dist = (sqd[i] - 2.0 * acc) + sqd[j];
      key = enc_dist(dist) | (u64)(u32)j;
    }
  }
  ks[lane] = key;
  __syncthreads();
  if (lane == 0) {
    u64 out[10];
#pragma unroll
    for (int s = 0; s < 10; ++s) out[s] = ~0ull;
    for (int m = 0; m < 128; ++m) {
      const u64 k = ks[m];
      if (k < out[9]) {
        int pos = 9;
        while (pos > 0 && out[pos - 1] > k) { out[pos] = out[pos - 1]; --pos; }
        out[pos] = k;
      }
    }
#pragma unroll
    for (int s = 0; s < 10; ++s) keys10[(size_t)i * 10 + s] = out[s];
  }
}

// ---------------- CSR build ----------------
__global__ void zero_ints(int* __restrict__ p, int n) {
  const int i = blockIdx.x * 256 + threadIdx.x;
  if (i < n) p[i] = 0;
}
__global__ void hist_tgt(const int* __restrict__ tgt, int* __restrict__ deg) {
  const int e = blockIdx.x * 256 + threadIdx.x;
  if (e < NE) atomicAdd(&deg[tgt[e]], 1);
}
__global__ __launch_bounds__(1024) void scan_deg(const int* __restrict__ deg, int* __restrict__ off) {
  __shared__ int ps[1024];
  const int tid = threadIdx.x;
  const int base = tid * 8;
  int v[8];
  int s = 0;
#pragma unroll
  for (int q = 0; q < 8; ++q) { v[q] = deg[base + q]; s += v[q]; }
  ps[tid] = s;
  __syncthreads();
  for (int d = 1; d < 1024; d <<= 1) {
    const int add = (tid >= d) ? ps[tid - d] : 0;
    __syncthreads();
    ps[tid] += add;
    __syncthreads();
  }
  int run = (tid == 0) ? 0 : ps[tid - 1];
#pragma unroll
  for (int q = 0; q < 8; ++q) { off[base + q] = run; run += v[q]; }
  if (tid == 1023) off[NN] = run;
}
__global__ void scatter_edges(const int* __restrict__ tgt, const int* __restrict__ off,
                              int* __restrict__ cur, int* __restrict__ perm) {
  const int e = blockIdx.x * 256 + threadIdx.x;
  if (e < NE) {
    const int t = tgt[e];
    const int p = atomicAdd(&cur[t], 1);
    perm[off[t] + p] = e;
  }
}

// ---------------- spatial edge logits ----------------
__global__ __launch_bounds__(256) void edge_logits_sp(
    const float* __restrict__ xl, const float* __restrict__ xr,
    const float* __restrict__ att, const float* __restrict__ we,
    const float* __restrict__ ea, const int* __restrict__ srcv, const int* __restrict__ tgtv,
    float* __restrict__ logits) {
  const int e = blockIdx.x * 4 + (threadIdx.x >> 6);
  const int lane = threadIdx.x & 63;
  const int s = srcv[e], t = tgtv[e];
  const float w = ea[e];
  const float* pl = xl + (size_t)s * DD;
  const float* pr = xr + (size_t)t * DD;
  double acc = 0.0;
#pragma unroll
  for (int b = 0; b < DD; b += 256) {
    const int d = b + lane * 4;
    const float4 a4 = *reinterpret_cast<const float4*>(&pl[d]);
    const float4 r4 = *reinterpret_cast<const float4*>(&pr[d]);
    const float4 w4 = *reinterpret_cast<const float4*>(&we[d]);
    const float4 t4 = *reinterpret_cast<const float4*>(&att[d]);
    acc += (double)t4.x * (double)lrelu32(a4.x + r4.x + w * w4.x);
    acc += (double)t4.y * (double)lrelu32(a4.y + r4.y + w * w4.y);
    acc += (double)t4.z * (double)lrelu32(a4.z + r4.z + w * w4.z);
    acc += (double)t4.w * (double)lrelu32(a4.w + r4.w + w * w4.w);
  }
#pragma unroll
  for (int o = 32; o > 0; o >>= 1) acc += __shfl_down(acc, o);
  if (lane == 0) logits[e] = (float)acc;
}

// ---------------- fused per-target: spatial softmax-agg + hedged latent GAT + relu6 ----------------
__global__ __launch_bounds__(256) void gat_aggregate_fused(
    const float* __restrict__ xls, const float* __restrict__ lgsp,
    const int* __restrict__ off, const int* __restrict__ perm, const int* __restrict__ srcv,
    const float* __restrict__ bias_sp,
    const float* __restrict__ xll, const float* __restrict__ xrl,
    const float* __restrict__ att,
    const u64* __restrict__ keys10, const int* __restrict__ flg_in, int* __restrict__ flg_out,
    const float* __restrict__ bias_lat, float* __restrict__ hout) {
  const int t = blockIdx.x;
  const int tid = threadIdx.x;
  const int lane = tid & 63, wid = tid >> 6;
  __shared__ double lg[9];
  __shared__ double sm[2];
  __shared__ int nidx[10];
  __shared__ int marked;
  __shared__ double gap;
  __shared__ float red[256];
  if (tid < 10) nidx[tid] = (int)(keys10[(size_t)t * 10 + tid] & 0x1FFFull);
  if (tid == 0) gap = dec_key(keys10[(size_t)t * 10 + 8]) - dec_key(keys10[(size_t)t * 10 + 7]);
  __syncthreads();
  if (tid == 0) {
    int m = flg_in[t];
#pragma unroll
    for (int q = 0; q < 10; ++q) m |= flg_in[nidx[q]];
    marked = m;
  }
  const float* pr = xrl + (size_t)t * DD;
  for (int q = wid; q < 9; q += 4) {
    const float* pl = xll + (size_t)nidx[q] * DD;
    double acc = 0.0;
#pragma unroll
    for (int b = 0; b < DD; b += 256) {
      const int d = b + lane * 4;
      const float4 a4 = *reinterpret_cast<const float4*>(&pl[d]);
      const float4 r4 = *reinterpret_cast<const float4*>(&pr[d]);
      const float4 t4 = *reinterpret_cast<const float4*>(&att[d]);
      acc += (double)t4.x * (double)lrelu32(a4.x + r4.x);
      acc += (double)t4.y * (double)lrelu32(a4.y + r4.y);
      acc += (double)t4.z * (double)lrelu32(a4.z + r4.z);
      acc += (double)t4.w * (double)lrelu32(a4.w + r4.w);
    }
#pragma unroll
    for (int o = 32; o > 0; o >>= 1) acc += __shfl_down(acc, o);
    if (lane == 0) lg[q] = acc;
  }
  const int o0 = off[t];
  const int deg = off[t + 1] - o0;
  if (tid < 64 && deg > 0) {
    double mx = -INFINITY;
    for (int m = lane; m < deg; m += 64) mx = fmax(mx, (double)lgsp[perm[o0 + m]]);
#pragma unroll
    for (int o = 32; o > 0; o >>= 1) mx = fmax(mx, __shfl_down(mx, o));
    mx = __shfl(mx, 0);
    double ss = 0.0;
    for (int m = lane; m < deg; m += 64) ss += exp((double)lgsp[perm[o0 + m]] - mx);
#pragma unroll
    for (int o = 32; o > 0; o >>= 1) ss += __shfl_down(ss, o);
    if (lane == 0) { sm[0] = mx; sm[1] = ss; }
  }
  __syncthreads();
  double a0 = 0.0, a1 = 0.0;
  if (deg > 0) {
    const double mx = sm[0], stot = sm[1];
    for (int m = 0; m < deg; ++m) {
      const int e = perm[o0 + m];
      const int s = srcv[e];
      const double a = exp((double)lgsp[e] - mx) / stot;
      a0 = fma(a, (double)xls[(size_t)s * DD + tid], a0);
      a1 = fma(a, (double)xls[(size_t)s * DD + 256 + tid], a1);
    }
  }
  double mA = lg[0], mB = lg[8];
#pragma unroll
  for (int q = 1; q < 8; ++q) mA = fmax(mA, lg[q]);
#pragma unroll
  for (int q = 0; q < 7; ++q) mB = fmax(mB, lg[q]);
  double eA[8], eB[8];
  double sA = 0.0, sB = 0.0;
#pragma unroll
  for (int q = 0; q < 8; ++q) { eA[q] = exp(lg[q] - mA); sA += eA[q]; }
#pragma unroll
  for (int q = 0; q < 7; ++q) { eB[q] = exp(lg[q] - mB); sB += eB[q]; }
  eB[7] = exp(lg[8] - mB); sB += eB[7];
  double A0 = 0.0, A1 = 0.0, B0 = 0.0, B1 = 0.0;
#pragma unroll
  for (int q = 0; q < 8; ++q) {
    const double x0 = (double)xll[(size_t)nidx[q] * DD + tid];
    const double x1 = (double)xll[(size_t)nidx[q] * DD + 256 + tid];
    A0 = fma(eA[q], x0, A0);
    A1 = fma(eA[q], x1, A1);
    if (q < 7) { B0 = fma(eB[q], x0, B0); B1 = fma(eB[q], x1, B1); }
  }
  {
    const double x0 = (double)xll[(size_t)nidx[8] * DD + tid];
    const double x1 = (double)xll[(size_t)nidx[8] * DD + 256 + tid];
    B0 = fma(eB[7], x0, B0);
    B1 = fma(eB[7], x1, B1);
  }
  const double sp0 = a0 + (double)bias_sp[tid];
  const double sp1 = a1 + (double)bias_sp[tid + 256];
  const double bl0 = (double)bias_lat[tid];
  const double bl1 = (double)bias_lat[tid + 256];
  const double vA0 = fmin(fmax(sp0 + (A0 / sA + bl0), 0.0), 6.0);
  const double vA1 = fmin(fmax(sp1 + (A1 / sA + bl1), 0.0), 6.0);
  const double vB0 = fmin(fmax(sp0 + (B0 / sB + bl0), 0.0), 6.0);
  const double vB1 = fmin(fmax(sp1 + (B1 / sB + bl1), 0.0), 6.0);
  red[tid] = fmaxf((float)fabs(vA0 - vB0), (float)fabs(vA1 - vB1));
  __syncthreads();
  for (int s = 128; s > 0; s >>= 1) {
    if (tid < s) red[tid] = fmaxf(red[tid], red[tid + s]);
    __syncthreads();
  }
  const double eps = marked ? EPS_MARK : EPS_BASE;
  const double w = (gap < eps && red[0] <= DMAX_HEDGE) ? 0.5 : 0.0;
  if (tid == 0) flg_out[t] = (w > 0.0) ? 1 : 0;
  hout[(size_t)t * DD + tid]       = (float)((1.0 - w) * vA0 + w * vB0);
  hout[(size_t)t * DD + 256 + tid] = (float)((1.0 - w) * vA1 + w * vB1);
}

extern "C" void kernel_launch(void* const* d_in, const int* in_sizes, int n_in,
                              void* d_out, int out_size, void* d_ws, size_t ws_size,
                              hipStream_t stream) {
  const float* x       = (const float*)d_in[0];
  const float* ea      = (const float*)d_in[1];
  const float* W0      = (const float*)d_in[2];
  const float* b0      = (const float*)d_in[3];
  const float* W1      = (const float*)d_in[4];
  const float* b1      = (const float*)d_in[5];
  const float* W2      = (const float*)d_in[6];
  const float* b2      = (const float*)d_in[7];
  const float* Wl_sp   = (const float*)d_in[8];
  const float* bl_sp   = (const float*)d_in[9];
  const float* Wr_sp   = (const float*)d_in[10];
  const float* br_sp   = (const float*)d_in[11];
  const float* att_sp  = (const float*)d_in[12];
  const float* bias_sp = (const float*)d_in[13];
  const float* We_sp   = (const float*)d_in[14];
  const float* Wl_lat  = (const float*)d_in[15];
  const float* bl_lat  = (const float*)d_in[16];
  const float* Wr_lat  = (const float*)d_in[17];
  const float* br_lat  = (const float*)d_in[18];
  const float* att_lat = (const float*)d_in[19];
  const float* bias_lat= (const float*)d_in[20];
  const int*   eidx    = (const int*)d_in[21];
  const int* srcv = eidx;
  const int* tgtv = eidx + NE;

  char* ws = (char*)d_ws;
  size_t off = 0;
  auto alloc = [&](size_t bytes) -> void* {
    void* p = ws + off;
    off = (off + bytes + 255) & ~(size_t)255;
    return p;
  };
  float* h0     = (float*)alloc((size_t)NN * DD * 4);
  float* h1     = (float*)alloc((size_t)NN * DD * 4);
  float* xls    = (float*)alloc((size_t)NN * DD * 4);
  float* xrs    = (float*)alloc((size_t)NN * DD * 4);
  float* xll    = (float*)alloc((size_t)NN * DD * 4);
  float* xrl    = (float*)alloc((size_t)NN * DD * 4);
  float* logits = (float*)alloc((size_t)NE * 4);
  double* sqd   = (double*)alloc((size_t)NN * 8);
  float* sqf    = (float*)alloc((size_t)NN * 4);
  ushortx* Hhi  = (ushortx*)alloc((size_t)NN * DD * 2);
  ushortx* Hlo  = (ushortx*)alloc((size_t)NN * DD * 2);
  float* Dst    = (float*)alloc((size_t)NN * STRIPW * 4);
  int* cand     = (int*)alloc((size_t)NN * NCAND * 4);
  u64* keys10   = (u64*)alloc((size_t)NN * 10 * 8);
  int* flags0   = (int*)alloc((size_t)NN * 4);
  int* flags1   = (int*)alloc((size_t)NN * 4);
  int* flags2   = (int*)alloc((size_t)NN * 4);
  int* deg      = (int*)alloc((size_t)NN * 4);
  int* offs     = (int*)alloc((size_t)(NN + 1) * 4);
  int* cur      = (int*)alloc((size_t)NN * 4);
  int* perm     = (int*)alloc((size_t)NE * 4);
  float* t1 = xls;
  float* t2 = xrs;

  // MLP encoder
  gemm_bias_act<1><<<dim3(512 / 64, NN / 64), 256, 0, stream>>>(x, W0, b0, t1, D_IN, 512);
  gemm_bias_act<1><<<dim3(256 / 64, NN / 64), 256, 0, stream>>>(t1, W1, b1, t2, 512, 256);
  gemm_bias_act<0><<<dim3(512 / 64, NN / 64), 256, 0, stream>>>(t2, W2, b2, h0, 256, 512);

  // CSR of spatial edges by target
  zero_ints<<<NN / 256, 256, 0, stream>>>(deg, NN);
  zero_ints<<<NN / 256, 256, 0, stream>>>(cur, NN);
  zero_ints<<<NN / 256, 256, 0, stream>>>(flags0, NN);
  hist_tgt<<<NE / 256, 256, 0, stream>>>(tgtv, deg);
  scan_deg<<<1, 1024, 0, stream>>>(deg, offs);
  scatter_edges<<<NE / 256, 256, 0, stream>>>(tgtv, offs, cur, perm);

  for (int l = 0; l < 2; ++l) {
    const float* hin = l ? h1 : h0;
    float* hout = l ? (float*)d_out : h1;
    const int* fin  = l ? flags1 : flags0;
    int* fout       = l ? flags2 : flags1;
    const size_t wofs = (size_t)l * DD * DD;
    const size_t vofs = (size_t)l * DD;
    gemm_bias_act<0><<<dim3(8, 128), 256, 0, stream>>>(hin, Wl_sp + wofs, bl_sp + vofs, xls, DD, DD);
    gemm_bias_act<0><<<dim3(8, 128), 256, 0, stream>>>(hin, Wr_sp + wofs, br_sp + vofs, xrs, DD, DD);
    gemm_bias_act<0><<<dim3(8, 128), 256, 0, stream>>>(hin, Wl_lat + wofs, bl_lat + vofs, xll, DD, DD);
    gemm_bias_act<0><<<dim3(8, 128), 256, 0, stream>>>(hin, Wr_lat + wofs, br_lat + vofs, xrl, DD, DD);
    row_sqnorm_d<<<NN / 4, 256, 0, stream>>>(hin, sqd, sqf);
    hsplit<<<(NN * DD / 4) / 256, 256, 0, stream>>>(hin, Hhi, Hlo);
    for (int s = 0; s < NSTRIP; ++s) {
      gram_strip<<<dim3(STRIPW / 64, NN / 64), 256, 0, stream>>>(Hhi, Hlo, sqf, s * STRIPW, Dst);
      knn_scan<<<NN / 4, 256, 0, stream>>>(Dst, s * STRIPW, cand, s * CPS);
    }
    knn_refine10<<<NN, 128, 0, stream>>>(hin, sqd, cand, keys10);
    edge_logits_sp<<<NE / 4, 256, 0, stream>>>(xls, xrs, att_sp + vofs, We_sp + vofs, ea, srcv, tgtv, logits);
    gat_aggregate_fused<<<NN, 256, 0, stream>>>(
        xls, logits, offs, perm, srcv, bias_sp + vofs,
        xll, xrl, att_lat + vofs, keys10, fin, fout, bias_lat + vofs, hout);
  }
}

// Round 18
// 3273.782 us; speedup vs baseline: 1.2345x; 1.1464x over previous
//
#include <hip/hip_runtime.h>
#include <cstdint>
#include <cstddef>

#define NN 8192
#define D_IN 1024
#define DD 512
#define NE 131072
#define KK 8

#define STRIPW 2048
#define NSTRIP 4
#define CPS 24
#define NCAND 96

#define EPS_BASE 0.0035
#define EPS_MARK 0.10
#define DMAX_HEDGE 0.066f

typedef unsigned long long u64;
typedef unsigned int u32;
typedef unsigned short ushortx;
typedef __attribute__((ext_vector_type(8))) short short8v;
typedef __attribute__((ext_vector_type(16))) float f32x16;

__device__ __forceinline__ float lrelu32(float v) { return v >= 0.0f ? v : 0.2f * v; }

__device__ __forceinline__ u64 enc_dist(double dist) {
  u64 b = (u64)__double_as_longlong(dist);
  b = (b >> 63) ? ~b : (b | 0x8000000000000000ull);
  return b & 0xFFFFFFFFFFFFE000ull;
}
__device__ __forceinline__ double dec_key(u64 k) {
  u64 ub = k & 0xFFFFFFFFFFFFE000ull;
  u64 b = (ub >> 63) ? (ub & 0x7FFFFFFFFFFFFFFFull) : ~ub;
  return __longlong_as_double((long long)b);
}
__device__ __forceinline__ u32 enc_f32(float d) {
  u32 ub = __float_as_uint(d);
  return (ub & 0x80000000u) ? ~ub : (ub | 0x80000000u);
}
__device__ __forceinline__ ushortx f2bf(float f) {
  u32 u = __float_as_uint(f);
  return (ushortx)((u + 0x7FFFu + ((u >> 16) & 1u)) >> 16);
}

// ---------------- tiled GEMM: fp32 in/out, fp64 accumulate -- double-buffered (bit-exact chain) ----------------
template<int ACT>
__global__ __launch_bounds__(256) void gemm_bias_act(
    const float* __restrict__ A, const float* __restrict__ W,
    const float* __restrict__ bias, float* __restrict__ C,
    int K, int Nc) {
  __shared__ float As[2][16][68];
  __shared__ float Bs[2][16][68];
  const int tid = threadIdx.x;
  const int tx = tid & 15, ty = tid >> 4;
  const int row0 = blockIdx.y * 64, col0 = blockIdx.x * 64;
  const int ar = tid >> 2, akq = (tid & 3) << 2;
  const int br = tid >> 4, bc = (tid & 15) << 2;
  double acc[4][4] = {};
  {
    const float4 av = *reinterpret_cast<const float4*>(&A[(size_t)(row0 + ar) * K + akq]);
    As[0][akq + 0][ar] = av.x; As[0][akq + 1][ar] = av.y; As[0][akq + 2][ar] = av.z; As[0][akq + 3][ar] = av.w;
    const float4 bv = *reinterpret_cast<const float4*>(&W[(size_t)br * Nc + (col0 + bc)]);
    Bs[0][br][bc + 0] = bv.x; Bs[0][br][bc + 1] = bv.y; Bs[0][br][bc + 2] = bv.z; Bs[0][br][bc + 3] = bv.w;
  }
  __syncthreads();
  int buf = 0;
  for (int k0 = 0; k0 < K; k0 += 16) {
    float4 av, bv;
    const bool more = (k0 + 16) < K;
    if (more) {
      av = *reinterpret_cast<const float4*>(&A[(size_t)(row0 + ar) * K + (k0 + 16 + akq)]);
      bv = *reinterpret_cast<const float4*>(&W[(size_t)(k0 + 16 + br) * Nc + (col0 + bc)]);
    }
#pragma unroll
    for (int kk = 0; kk < 16; ++kk) {
      const float4 a4 = *reinterpret_cast<const float4*>(&As[buf][kk][ty << 2]);
      const float4 b4 = *reinterpret_cast<const float4*>(&Bs[buf][kk][tx << 2]);
      double a[4], b[4];
      a[0] = (double)a4.x; a[1] = (double)a4.y; a[2] = (double)a4.z; a[3] = (double)a4.w;
      b[0] = (double)b4.x; b[1] = (double)b4.y; b[2] = (double)b4.z; b[3] = (double)b4.w;
#pragma unroll
      for (int i = 0; i < 4; ++i)
#pragma unroll
        for (int j = 0; j < 4; ++j) acc[i][j] = fma(a[i], b[j], acc[i][j]);
    }
    if (more) {
      const int nb = buf ^ 1;
      As[nb][akq + 0][ar] = av.x; As[nb][akq + 1][ar] = av.y; As[nb][akq + 2][ar] = av.z; As[nb][akq + 3][ar] = av.w;
      Bs[nb][br][bc + 0] = bv.x; Bs[nb][br][bc + 1] = bv.y; Bs[nb][br][bc + 2] = bv.z; Bs[nb][br][bc + 3] = bv.w;
      __syncthreads();
      buf = nb;
    }
  }
#pragma unroll
  for (int i = 0; i < 4; ++i) {
    const int r = row0 + (ty << 2) + i;
#pragma unroll
    for (int j = 0; j < 4; ++j) {
      const int c = col0 + (tx << 2) + j;
      double v = acc[i][j] + (double)bias[c];
      if (ACT) v = fmin(fmax(v, 0.0), 6.0);
      C[(size_t)r * Nc + c] = (float)v;
    }
  }
}

// ---------------- row squared norms ----------------
__global__ __launch_bounds__(256) void row_sqnorm_d(const float* __restrict__ H,
                                                    double* __restrict__ sqd,
                                                    float* __restrict__ sqf) {
  const int row = blockIdx.x * 4 + (threadIdx.x >> 6);
  const int lane = threadIdx.x & 63;
  const float* h = H + (size_t)row * DD;
  double s = 0.0;
#pragma unroll
  for (int b = 0; b < DD; b += 256) {
    const float4 v = *reinterpret_cast<const float4*>(&h[b + lane * 4]);
    s += (double)v.x * v.x + (double)v.y * v.y + (double)v.z * v.z + (double)v.w * v.w;
  }
#pragma unroll
  for (int o = 32; o > 0; o >>= 1) s += __shfl_down(s, o);
  if (lane == 0) { sqd[row] = s; sqf[row] = (float)s; }
}

// ---------------- H -> bf16 (candidate pass; 1-pass bf16 Gram error ~0.1 << rank-10..96 gap) ----------------
__global__ __launch_bounds__(256) void hsplit(const float* __restrict__ H,
                                              ushortx* __restrict__ Hhi) {
  const int base = (blockIdx.x * 256 + threadIdx.x) * 4;
  const float4 v = *reinterpret_cast<const float4*>(&H[base]);
  const float f[4] = {v.x, v.y, v.z, v.w};
  ushortx hi[4];
#pragma unroll
  for (int q = 0; q < 4; ++q) hi[q] = f2bf(f[q]);
  *reinterpret_cast<ushort4*>(&Hhi[base]) = make_ushort4(hi[0], hi[1], hi[2], hi[3]);
}

// ---------------- MFMA bf16 Gram strip (single pass) ----------------
__global__ __launch_bounds__(256) void gram_strip(
    const ushortx* __restrict__ Hhi,
    const float* __restrict__ sqf, int jbase, float* __restrict__ Dst) {
  __shared__ uint4 Ah4[256], Bh4[256];
  const int tid = threadIdx.x;
  const int w = tid >> 6, lane = tid & 63;
  const int wr = w >> 1, wc = w & 1;
  const int i0 = blockIdx.y * 64;
  const int j0 = jbase + blockIdx.x * 64;
  const int rh = tid >> 7, skk = (tid >> 6) & 1, sg = (tid >> 5) & 1, sr = tid & 31;
  const size_t arow = (size_t)(i0 + rh * 32 + sr) * DD;
  const size_t brow = (size_t)(j0 + rh * 32 + sr) * DD;
  const int koff = skk * 16 + sg * 8;
  f32x16 acc0;
#pragma unroll
  for (int e = 0; e < 16; ++e) acc0[e] = 0.0f;

  for (int k0 = 0; k0 < DD; k0 += 32) {
    __syncthreads();
    Ah4[tid] = *reinterpret_cast<const uint4*>(&Hhi[arow + k0 + koff]);
    Bh4[tid] = *reinterpret_cast<const uint4*>(&Hhi[brow + k0 + koff]);
    __syncthreads();
    const short8v* Ah = reinterpret_cast<const short8v*>(Ah4);
    const short8v* Bh = reinterpret_cast<const short8v*>(Bh4);
    const short8v ah0 = Ah[(wr * 2 + 0) * 64 + lane];
    const short8v ah1 = Ah[(wr * 2 + 1) * 64 + lane];
    const short8v bh0 = Bh[(wc * 2 + 0) * 64 + lane];
    const short8v bh1 = Bh[(wc * 2 + 1) * 64 + lane];
    acc0 = __builtin_amdgcn_mfma_f32_32x32x16_bf16(ah0, bh0, acc0, 0, 0, 0);
    acc0 = __builtin_amdgcn_mfma_f32_32x32x16_bf16(ah1, bh1, acc0, 0, 0, 0);
  }
  const int ccol = j0 + wc * 32 + (lane & 31);
  const float sqc = sqf[ccol];
#pragma unroll
  for (int reg = 0; reg < 16; ++reg) {
    const int row = i0 + wr * 32 + (reg & 3) + 8 * (reg >> 2) + 4 * (lane >> 5);
    const float G = acc0[reg];
    float d = (sqf[row] - 2.0f * G) + sqc;
    if (row == ccol) d = INFINITY;
    Dst[(size_t)row * STRIPW + (ccol - jbase)] = d;
  }
}

// ---------------- per-row strip scan ----------------
__global__ __launch_bounds__(256) void knn_scan(
    const float* __restrict__ Dst, int jbase, int* __restrict__ cand, int soff) {
  const int w = threadIdx.x >> 6, lane = threadIdx.x & 63;
  const int row = blockIdx.x * 4 + w;
  const float* dr = Dst + (size_t)row * STRIPW;
  u64 best[8];
#pragma unroll
  for (int s = 0; s < 8; ++s) best[s] = ~0ull;
#pragma unroll
  for (int it = 0; it < STRIPW / 256; ++it) {
    const int cbase = it * 256 + lane * 4;
    const float4 v = *reinterpret_cast<const float4*>(&dr[cbase]);
    const float f[4] = {v.x, v.y, v.z, v.w};
#pragma unroll
    for (int q = 0; q < 4; ++q) {
      const u64 key = ((u64)enc_f32(f[q]) << 32) | (u32)(jbase + cbase + q);
      if (key < best[7]) {
        best[7] = key;
#pragma unroll
        for (int s = 7; s >= 1; --s) {
          if (best[s] < best[s - 1]) { const u64 t = best[s]; best[s] = best[s - 1]; best[s - 1] = t; }
        }
      }
    }
  }
  for (int t = 0; t < CPS; ++t) {
    u64 m = best[0];
#pragma unroll
    for (int o = 32; o > 0; o >>= 1) {
      const u64 x = __shfl_xor(m, o);
      m = (x < m) ? x : m;
    }
    const unsigned long long mask = __ballot(best[0] == m);
    const int owner = __ffsll(mask) - 1;
    if (lane == owner) {
#pragma unroll
      for (int s = 0; s < 7; ++s) best[s] = best[s + 1];
      best[7] = ~0ull;
    }
    if (lane == 0) cand[(size_t)row * NCAND + soff + t] = (int)(m & 0x1FFFull);
  }
}

// ---------------- EXACT refinement: fp64 sequential dot (r14-proven form) ----------------
__global__ __launch_bounds__(128) void knn_refine10(
    const float* __restrict__ H, const double* __restrict__ sqd,
    const int* __restrict__ cand, u64* __restrict__ keys10) {
  const int i = blockIdx.x;
  const int lane = threadIdx.x;
  __shared__ float hi[DD];
  __shared__ u64 ks[128];
  for (int d = lane; d < DD; d += 128) hi[d] = H[(size_t)i * DD + d];
  __syncthreads();
  u64 key = ~0ull;
  if (lane < NCAND) {
    const int j = cand[(size_t)i * NCAND + lane];
    if (j != i) {
      const float* hj = H + (size_t)j * DD;
      double acc = 0.0;
#pragma unroll 16
      for (int k = 0; k < DD; ++k) acc = fma((double)hi[k], (double)hj[k], acc);
      const double dist = (sqd[i] - 2.0 * acc) + sqd[j];
      key = enc_dist(dist) | (u64)(u32)j;
    }
  }
  ks[lane] = key;
  __syncthreads();
  if (lane == 0) {
    u64 out[10];
#pragma unroll
    for (int s = 0; s < 10; ++s) out[s] = ~0ull;
    for (int m = 0; m < 128; ++m) {
      const u64 k = ks[m];
      if (k < out[9]) {
        int pos = 9;
        while (pos > 0 && out[pos - 1] > k) { out[pos] = out[pos - 1]; --pos; }
        out[pos] = k;
      }
    }
#pragma unroll
    for (int s = 0; s < 10; ++s) keys10[(size_t)i * 10 + s] = out[s];
  }
}

// ---------------- CSR build ----------------
__global__ void zero_ints(int* __restrict__ p, int n) {
  const int i = blockIdx.x * 256 + threadIdx.x;
  if (i < n) p[i] = 0;
}
__global__ void hist_tgt(const int* __restrict__ tgt, int* __restrict__ deg) {
  const int e = blockIdx.x * 256 + threadIdx.x;
  if (e < NE) atomicAdd(&deg[tgt[e]], 1);
}
__global__ __launch_bounds__(1024) void scan_deg(const int* __restrict__ deg, int* __restrict__ off) {
  __shared__ int ps[1024];
  const int tid = threadIdx.x;
  const int base = tid * 8;
  int v[8];
  int s = 0;
#pragma unroll
  for (int q = 0; q < 8; ++q) { v[q] = deg[base + q]; s += v[q]; }
  ps[tid] = s;
  __syncthreads();
  for (int d = 1; d < 1024; d <<= 1) {
    const int add = (tid >= d) ? ps[tid - d] : 0;
    __syncthreads();
    ps[tid] += add;
    __syncthreads();
  }
  int run = (tid == 0) ? 0 : ps[tid - 1];
#pragma unroll
  for (int q = 0; q < 8; ++q) { off[base + q] = run; run += v[q]; }
  if (tid == 1023) off[NN] = run;
}
__global__ void scatter_edges(const int* __restrict__ tgt, const int* __restrict__ off,
                              int* __restrict__ cur, int* __restrict__ perm) {
  const int e = blockIdx.x * 256 + threadIdx.x;
  if (e < NE) {
    const int t = tgt[e];
    const int p = atomicAdd(&cur[t], 1);
    perm[off[t] + p] = e;
  }
}

// ---------------- spatial edge logits ----------------
__global__ __launch_bounds__(256) void edge_logits_sp(
    const float* __restrict__ xl, const float* __restrict__ xr,
    const float* __restrict__ att, const float* __restrict__ we,
    const float* __restrict__ ea, const int* __restrict__ srcv, const int* __restrict__ tgtv,
    float* __restrict__ logits) {
  const int e = blockIdx.x * 4 + (threadIdx.x >> 6);
  const int lane = threadIdx.x & 63;
  const int s = srcv[e], t = tgtv[e];
  const float w = ea[e];
  const float* pl = xl + (size_t)s * DD;
  const float* pr = xr + (size_t)t * DD;
  double acc = 0.0;
#pragma unroll
  for (int b = 0; b < DD; b += 256) {
    const int d = b + lane * 4;
    const float4 a4 = *reinterpret_cast<const float4*>(&pl[d]);
    const float4 r4 = *reinterpret_cast<const float4*>(&pr[d]);
    const float4 w4 = *reinterpret_cast<const float4*>(&we[d]);
    const float4 t4 = *reinterpret_cast<const float4*>(&att[d]);
    acc += (double)t4.x * (double)lrelu32(a4.x + r4.x + w * w4.x);
    acc += (double)t4.y * (double)lrelu32(a4.y + r4.y + w * w4.y);
    acc += (double)t4.z * (double)lrelu32(a4.z + r4.z + w * w4.z);
    acc += (double)t4.w * (double)lrelu32(a4.w + r4.w + w * w4.w);
  }
#pragma unroll
  for (int o = 32; o > 0; o >>= 1) acc += __shfl_down(acc, o);
  if (lane == 0) logits[e] = (float)acc;
}

// ---------------- fused per-target: spatial softmax-agg + hedged latent GAT + relu6 ----------------
__global__ __launch_bounds__(256) void gat_aggregate_fused(
    const float* __restrict__ xls, const float* __restrict__ lgsp,
    const int* __restrict__ off, const int* __restrict__ perm, const int* __restrict__ srcv,
    const float* __restrict__ bias_sp,
    const float* __restrict__ xll, const float* __restrict__ xrl,
    const float* __restrict__ att,
    const u64* __restrict__ keys10, const int* __restrict__ flg_in, int* __restrict__ flg_out,
    const float* __restrict__ bias_lat, float* __restrict__ hout) {
  const int t = blockIdx.x;
  const int tid = threadIdx.x;
  const int lane = tid & 63, wid = tid >> 6;
  __shared__ double lg[9];
  __shared__ double sm[2];
  __shared__ int nidx[10];
  __shared__ int marked;
  __shared__ double gap;
  __shared__ float red[256];
  if (tid < 10) nidx[tid] = (int)(keys10[(size_t)t * 10 + tid] & 0x1FFFull);
  if (tid == 0) gap = dec_key(keys10[(size_t)t * 10 + 8]) - dec_key(keys10[(size_t)t * 10 + 7]);
  __syncthreads();
  if (tid == 0) {
    int m = flg_in[t];
#pragma unroll
    for (int q = 0; q < 10; ++q) m |= flg_in[nidx[q]];
    marked = m;
  }
  const float* pr = xrl + (size_t)t * DD;
  for (int q = wid; q < 9; q += 4) {
    const float* pl = xll + (size_t)nidx[q] * DD;
    double acc = 0.0;
#pragma unroll
    for (int b = 0; b < DD; b += 256) {
      const int d = b + lane * 4;
      const float4 a4 = *reinterpret_cast<const float4*>(&pl[d]);
      const float4 r4 = *reinterpret_cast<const float4*>(&pr[d]);
      const float4 t4 = *reinterpret_cast<const float4*>(&att[d]);
      acc += (double)t4.x * (double)lrelu32(a4.x + r4.x);
      acc += (double)t4.y * (double)lrelu32(a4.y + r4.y);
      acc += (double)t4.z * (double)lrelu32(a4.z + r4.z);
      acc += (double)t4.w * (double)lrelu32(a4.w + r4.w);
    }
#pragma unroll
    for (int o = 32; o > 0; o >>= 1) acc += __shfl_down(acc, o);
    if (lane == 0) lg[q] = acc;
  }
  const int o0 = off[t];
  const int deg = off[t + 1] - o0;
  if (tid < 64 && deg > 0) {
    double mx = -INFINITY;
    for (int m = lane; m < deg; m += 64) mx = fmax(mx, (double)lgsp[perm[o0 + m]]);
#pragma unroll
    for (int o = 32; o > 0; o >>= 1) mx = fmax(mx, __shfl_down(mx, o));
    mx = __shfl(mx, 0);
    double ss = 0.0;
    for (int m = lane; m < deg; m += 64) ss += exp((double)lgsp[perm[o0 + m]] - mx);
#pragma unroll
    for (int o = 32; o > 0; o >>= 1) ss += __shfl_down(ss, o);
    if (lane == 0) { sm[0] = mx; sm[1] = ss; }
  }
  __syncthreads();
  double a0 = 0.0, a1 = 0.0;
  if (deg > 0) {
    const double mx = sm[0], stot = sm[1];
    for (int m = 0; m < deg; ++m) {
      const int e = perm[o0 + m];
      const int s = srcv[e];
      const double a = exp((double)lgsp[e] - mx) / stot;
      a0 = fma(a, (double)xls[(size_t)s * DD + tid], a0);
      a1 = fma(a, (double)xls[(size_t)s * DD + 256 + tid], a1);
    }
  }
  double mA = lg[0], mB = lg[8];
#pragma unroll
  for (int q = 1; q < 8; ++q) mA = fmax(mA, lg[q]);
#pragma unroll
  for (int q = 0; q < 7; ++q) mB = fmax(mB, lg[q]);
  double eA[8], eB[8];
  double sA = 0.0, sB = 0.0;
#pragma unroll
  for (int q = 0; q < 8; ++q) { eA[q] = exp(lg[q] - mA); sA += eA[q]; }
#pragma unroll
  for (int q = 0; q < 7; ++q) { eB[q] = exp(lg[q] - mB); sB += eB[q]; }
  eB[7] = exp(lg[8] - mB); sB += eB[7];
  double A0 = 0.0, A1 = 0.0, B0 = 0.0, B1 = 0.0;
#pragma unroll
  for (int q = 0; q < 8; ++q) {
    const double x0 = (double)xll[(size_t)nidx[q] * DD + tid];
    const double x1 = (double)xll[(size_t)nidx[q] * DD + 256 + tid];
    A0 = fma(eA[q], x0, A0);
    A1 = fma(eA[q], x1, A1);
    if (q < 7) { B0 = fma(eB[q], x0, B0); B1 = fma(eB[q], x1, B1); }
  }
  {
    const double x0 = (double)xll[(size_t)nidx[8] * DD + tid];
    const double x1 = (double)xll[(size_t)nidx[8] * DD + 256 + tid];
    B0 = fma(eB[7], x0, B0);
    B1 = fma(eB[7], x1, B1);
  }
  const double sp0 = a0 + (double)bias_sp[tid];
  const double sp1 = a1 + (double)bias_sp[tid + 256];
  const double bl0 = (double)bias_lat[tid];
  const double bl1 = (double)bias_lat[tid + 256];
  const double vA0 = fmin(fmax(sp0 + (A0 / sA + bl0), 0.0), 6.0);
  const double vA1 = fmin(fmax(sp1 + (A1 / sA + bl1), 0.0), 6.0);
  const double vB0 = fmin(fmax(sp0 + (B0 / sB + bl0), 0.0), 6.0);
  const double vB1 = fmin(fmax(sp1 + (B1 / sB + bl1), 0.0), 6.0);
  red[tid] = fmaxf((float)fabs(vA0 - vB0), (float)fabs(vA1 - vB1));
  __syncthreads();
  for (int s = 128; s > 0; s >>= 1) {
    if (tid < s) red[tid] = fmaxf(red[tid], red[tid + s]);
    __syncthreads();
  }
  const double eps = marked ? EPS_MARK : EPS_BASE;
  const double w = (gap < eps && red[0] <= DMAX_HEDGE) ? 0.5 : 0.0;
  if (tid == 0) flg_out[t] = (w > 0.0) ? 1 : 0;
  hout[(size_t)t * DD + tid]       = (float)((1.0 - w) * vA0 + w * vB0);
  hout[(size_t)t * DD + 256 + tid] = (float)((1.0 - w) * vA1 + w * vB1);
}

extern "C" void kernel_launch(void* const* d_in, const int* in_sizes, int n_in,
                              void* d_out, int out_size, void* d_ws, size_t ws_size,
                              hipStream_t stream) {
  const float* x       = (const float*)d_in[0];
  const float* ea      = (const float*)d_in[1];
  const float* W0      = (const float*)d_in[2];
  const float* b0      = (const float*)d_in[3];
  const float* W1      = (const float*)d_in[4];
  const float* b1      = (const float*)d_in[5];
  const float* W2      = (const float*)d_in[6];
  const float* b2      = (const float*)d_in[7];
  const float* Wl_sp   = (const float*)d_in[8];
  const float* bl_sp   = (const float*)d_in[9];
  const float* Wr_sp   = (const float*)d_in[10];
  const float* br_sp   = (const float*)d_in[11];
  const float* att_sp  = (const float*)d_in[12];
  const float* bias_sp = (const float*)d_in[13];
  const float* We_sp   = (const float*)d_in[14];
  const float* Wl_lat  = (const float*)d_in[15];
  const float* bl_lat  = (const float*)d_in[16];
  const float* Wr_lat  = (const float*)d_in[17];
  const float* br_lat  = (const float*)d_in[18];
  const float* att_lat = (const float*)d_in[19];
  const float* bias_lat= (const float*)d_in[20];
  const int*   eidx    = (const int*)d_in[21];
  const int* srcv = eidx;
  const int* tgtv = eidx + NE;

  char* ws = (char*)d_ws;
  size_t off = 0;
  auto alloc = [&](size_t bytes) -> void* {
    void* p = ws + off;
    off = (off + bytes + 255) & ~(size_t)255;
    return p;
  };
  float* h0     = (float*)alloc((size_t)NN * DD * 4);
  float* h1     = (float*)alloc((size_t)NN * DD * 4);
  float* xls    = (float*)alloc((size_t)NN * DD * 4);
  float* xrs    = (float*)alloc((size_t)NN * DD * 4);
  float* xll    = (float*)alloc((size_t)NN * DD * 4);
  float* xrl    = (float*)alloc((size_t)NN * DD * 4);
  float* logits = (float*)alloc((size_t)NE * 4);
  double* sqd   = (double*)alloc((size_t)NN * 8);
  float* sqf    = (float*)alloc((size_t)NN * 4);
  ushortx* Hhi  = (ushortx*)alloc((size_t)NN * DD * 2);
  float* Dst    = (float*)alloc((size_t)NN * STRIPW * 4);
  int* cand     = (int*)alloc((size_t)NN * NCAND * 4);
  u64* keys10   = (u64*)alloc((size_t)NN * 10 * 8);
  int* flags0   = (int*)alloc((size_t)NN * 4);
  int* flags1   = (int*)alloc((size_t)NN * 4);
  int* flags2   = (int*)alloc((size_t)NN * 4);
  int* deg      = (int*)alloc((size_t)NN * 4);
  int* offs     = (int*)alloc((size_t)(NN + 1) * 4);
  int* cur      = (int*)alloc((size_t)NN * 4);
  int* perm     = (int*)alloc((size_t)NE * 4);
  float* t1 = xls;
  float* t2 = xrs;

  // MLP encoder
  gemm_bias_act<1><<<dim3(512 / 64, NN / 64), 256, 0, stream>>>(x, W0, b0, t1, D_IN, 512);
  gemm_bias_act<1><<<dim3(256 / 64, NN / 64), 256, 0, stream>>>(t1, W1, b1, t2, 512, 256);
  gemm_bias_act<0><<<dim3(512 / 64, NN / 64), 256, 0, stream>>>(t2, W2, b2, h0, 256, 512);

  // CSR of spatial edges by target
  zero_ints<<<NN / 256, 256, 0, stream>>>(deg, NN);
  zero_ints<<<NN / 256, 256, 0, stream>>>(cur, NN);
  zero_ints<<<NN / 256, 256, 0, stream>>>(flags0, NN);
  hist_tgt<<<NE / 256, 256, 0, stream>>>(tgtv, deg);
  scan_deg<<<1, 1024, 0, stream>>>(deg, offs);
  scatter_edges<<<NE / 256, 256, 0, stream>>>(tgtv, offs, cur, perm);

  for (int l = 0; l < 2; ++l) {
    const float* hin = l ? h1 : h0;
    float* hout = l ? (float*)d_out : h1;
    const int* fin  = l ? flags1 : flags0;
    int* fout       = l ? flags2 : flags1;
    const size_t wofs = (size_t)l * DD * DD;
    const size_t vofs = (size_t)l * DD;
    gemm_bias_act<0><<<dim3(8, 128), 256, 0, stream>>>(hin, Wl_sp + wofs, bl_sp + vofs, xls, DD, DD);
    gemm_bias_act<0><<<dim3(8, 128), 256, 0, stream>>>(hin, Wr_sp + wofs, br_sp + vofs, xrs, DD, DD);
    gemm_bias_act<0><<<dim3(8, 128), 256, 0, stream>>>(hin, Wl_lat + wofs, bl_lat + vofs, xll, DD, DD);
    gemm_bias_act<0><<<dim3(8, 128), 256, 0, stream>>>(hin, Wr_lat + wofs, br_lat + vofs, xrl, DD, DD);
    row_sqnorm_d<<<NN / 4, 256, 0, stream>>>(hin, sqd, sqf);
    hsplit<<<(NN * DD / 4) / 256, 256, 0, stream>>>(hin, Hhi);
    for (int s = 0; s < NSTRIP; ++s) {
      gram_strip<<<dim3(STRIPW / 64, NN / 64), 256, 0, stream>>>(Hhi, sqf, s * STRIPW, Dst);
      knn_scan<<<NN / 4, 256, 0, stream>>>(Dst, s * STRIPW, cand, s * CPS);
    }
    knn_refine10<<<NN, 128, 0, stream>>>(hin, sqd, cand, keys10);
    edge_logits_sp<<<NE / 4, 256, 0, stream>>>(xls, xrs, att_sp + vofs, We_sp + vofs, ea, srcv, tgtv, logits);
    gat_aggregate_fused<<<NN, 256, 0, stream>>>(
        xls, logits, offs, perm, srcv, bias_sp + vofs,
        xll, xrl, att_lat + vofs, keys10, fin, fout, bias_lat + vofs, hout);
  }
}